// Round 10
// baseline (60.387 us; speedup 1.0000x reference)
//
#include <hip/hip_runtime.h>
#include <hip/hip_bf16.h>

// RoI pooling (ROI-Align bilinear, A=7) on NHWC fp32 feature map.
// features_map: (1, 128, 128, 256) fp32
// boxes:        (2000, 4) int32  [x1, y1, x2, y2]
// out:          (2000, 1, 7, 7, 256) fp32
//
// Round-10: R7 single-kernel box sort + occupancy throttle.
//  - sort key: box CENTER bucket on an 8x8 grid, snake-ordered so
//    consecutive buckets are spatially adjacent.
//  - main kernel launched with 64 KB dynamic LDS (unused) -> 2 blocks/CU,
//    shrinking the device-wide in-flight window 2048 -> 512 blocks
//    (~21 concurrent boxes per XCD ~ 2-3.5 MB read working set, fits the
//    4 MiB per-XCD L2). R9 showed sort ORDER alone can't fix locality when
//    the occupancy WINDOW spans ~83 boxes (~15 MB) per XCD.
//  - chunked bijective XCD swizzle; nontemporal 100 MB output stores;
//    output written at original box index => sort-order invariant.

#define FM_H 128
#define FM_W 128
#define FM_C 256
#define ANCH 7
#define NSAMP (ANCH * ANCH)

typedef float f4 __attribute__((ext_vector_type(4)));

__global__ __launch_bounds__(256) void sort_boxes_kernel(
    const int* __restrict__ boxes, int* __restrict__ order, int n_boxes)
{
    __shared__ int cursor[64];
    const int tid = threadIdx.x;
    if (tid < 64) cursor[tid] = 0;
    __syncthreads();

    // bucket by box center, snake order over the 8x8 bucket grid
    for (int i = tid; i < n_boxes; i += 256) {
        const int xc = (boxes[i * 4 + 0] + boxes[i * 4 + 2]) >> 1;
        const int yc = (boxes[i * 4 + 1] + boxes[i * 4 + 3]) >> 1;
        const int yb = min(yc >> 4, 7);
        const int xb = min(xc >> 4, 7);
        const int key = (yb << 3) | ((yb & 1) ? (7 - xb) : xb);
        atomicAdd(&cursor[key], 1);
    }
    __syncthreads();

    if (tid == 0) {
        int run = 0;
        for (int k = 0; k < 64; ++k) {
            int c = cursor[k];
            cursor[k] = run;
            run += c;
        }
    }
    __syncthreads();

    for (int i = tid; i < n_boxes; i += 256) {
        const int xc = (boxes[i * 4 + 0] + boxes[i * 4 + 2]) >> 1;
        const int yc = (boxes[i * 4 + 1] + boxes[i * 4 + 3]) >> 1;
        const int yb = min(yc >> 4, 7);
        const int xb = min(xc >> 4, 7);
        const int key = (yb << 3) | ((yb & 1) ? (7 - xb) : xb);
        const int pos = atomicAdd(&cursor[key], 1);
        order[pos] = i;   // intra-bucket order nondeterministic; output invariant
    }
}

__global__ __launch_bounds__(256) void roi_pool_kernel(
    const float* __restrict__ fm,
    const int* __restrict__ boxes,
    const int* __restrict__ order,
    float* __restrict__ out,
    int n_samples)  // N * 49
{
    // chunked bijective XCD swizzle
    const int nb  = gridDim.x;
    const int b   = blockIdx.x;
    const int q   = nb >> 3;
    const int r   = nb & 7;
    const int xcd = b & 7;
    const int idx = b >> 3;
    const int sb  = (xcd < r ? xcd * (q + 1) : r * (q + 1) + (xcd - r) * q) + idx;

    const int lane = threadIdx.x & 63;
    // sample id in sorted order, wave-uniform on the scalar pipe
    const int wave = __builtin_amdgcn_readfirstlane((sb << 2) + (threadIdx.x >> 6));
    if (wave >= n_samples) return;

    const int sorted_box = wave / NSAMP;
    const int s   = wave - sorted_box * NSAMP;
    const int py  = s / ANCH;
    const int px  = s - py * ANCH;
    const int box = order[sorted_box];          // original box index

    const int x1 = boxes[box * 4 + 0];
    const int y1 = boxes[box * 4 + 1];
    const int x2 = boxes[box * 4 + 2];
    const int y2 = boxes[box * 4 + 3];

    // ---- axis_samples(y1, y2) at index py ----
    const float spany = (float)(y2 - y1);
    float sy = ((float)py + 0.5f) * (spany / (float)ANCH) - 0.5f;
    sy = fminf(fmaxf(sy, 0.0f), fmaxf(spany - 1.0f, 0.0f));
    const int iy0 = (int)floorf(sy);
    const int iy1 = min(iy0 + 1, y2 - y1 - 1);
    const float fy = sy - (float)iy0;
    const int ys0 = iy0 + y1;
    const int ys1 = iy1 + y1;

    // ---- axis_samples(x1, x2) at index px ----
    const float spanx = (float)(x2 - x1);
    float sx = ((float)px + 0.5f) * (spanx / (float)ANCH) - 0.5f;
    sx = fminf(fmaxf(sx, 0.0f), fmaxf(spanx - 1.0f, 0.0f));
    const int ix0 = (int)floorf(sx);
    const int ix1 = min(ix0 + 1, x2 - x1 - 1);
    const float fx = sx - (float)ix0;
    const int xs0 = ix0 + x1;
    const int xs1 = ix1 + x1;

    const f4* p00 = (const f4*)(fm + ((size_t)ys0 * FM_W + xs0) * FM_C);
    const f4* p01 = (const f4*)(fm + ((size_t)ys0 * FM_W + xs1) * FM_C);
    const f4* p10 = (const f4*)(fm + ((size_t)ys1 * FM_W + xs0) * FM_C);
    const f4* p11 = (const f4*)(fm + ((size_t)ys1 * FM_W + xs1) * FM_C);

    const f4 v00 = p00[lane];
    const f4 v01 = p01[lane];
    const f4 v10 = p10[lane];
    const f4 v11 = p11[lane];

    const float gx = 1.0f - fx;
    const float gy = 1.0f - fy;

    // Match reference order: x-lerp then y-lerp
    f4 res;
    #pragma unroll
    for (int c = 0; c < 4; ++c) {
        float top = v00[c] * gx + v01[c] * fx;
        float bot = v10[c] * gx + v11[c] * fx;
        res[c] = top * gy + bot * fy;
    }

    // write at ORIGINAL box position => output independent of sort order
    f4* dst = (f4*)(out + ((size_t)box * NSAMP + s) * FM_C);
    __builtin_nontemporal_store(res, &dst[lane]);
}

extern "C" void kernel_launch(void* const* d_in, const int* in_sizes, int n_in,
                              void* d_out, int out_size, void* d_ws, size_t ws_size,
                              hipStream_t stream) {
    const float* fm    = (const float*)d_in[0];   // (1,128,128,256) fp32
    const int*   boxes = (const int*)d_in[1];     // (N,4) int32
    // d_in[2] = anchor_size scalar (7); layout constants hard-coded to setup.

    const int N = in_sizes[1] / 4;
    const int n_samples = N * NSAMP;

    float* out  = (float*)d_out;
    int* order  = (int*)d_ws;                      // N ints of scratch

    sort_boxes_kernel<<<1, 256, 0, stream>>>(boxes, order, N);

    const int threads = 256;                       // 4 waves/block
    const int waves_per_block = threads / 64;
    const int grid = (n_samples + waves_per_block - 1) / waves_per_block;

    // 64 KB dynamic LDS (unused) throttles occupancy to 2 blocks/CU:
    // in-flight window 512 blocks device-wide -> per-XCD working set fits L2.
    roi_pool_kernel<<<grid, threads, 64 * 1024, stream>>>(fm, boxes, order, out,
                                                          n_samples);
}

// Round 11
// 35.955 us; speedup vs baseline: 1.6795x; 1.6795x over previous
//
#include <hip/hip_runtime.h>
#include <hip/hip_bf16.h>

// RoI pooling (ROI-Align bilinear, A=7) on NHWC fp32 feature map.
// features_map: (1, 128, 128, 256) fp32
// boxes:        (2000, 4) int32  [x1, y1, x2, y2]
// out:          (2000, 1, 7, 7, 256) fp32
//
// Round-11: exact R7 winner (34.4us: single-kernel box sort + chunked
// bijective XCD swizzle + full occupancy) with ONE change: plain cached
// stores instead of nontemporal. R10's counters showed FETCH_SIZE ~20MB
// (reads fully cached) and R9 showed read-order improvements are null =>
// the ~31us main kernel is suspected WRITE-DRAIN-bound (100 MB NT forced
// to HBM at ~4-5 TB/s ~ 20us floor). Working set (117 MB) fits the 256 MB
// L3, so cached writes in steady-state replay should be L3-absorbed.

#define FM_H 128
#define FM_W 128
#define FM_C 256
#define ANCH 7
#define NSAMP (ANCH * ANCH)

typedef float f4 __attribute__((ext_vector_type(4)));

__global__ __launch_bounds__(256) void sort_boxes_kernel(
    const int* __restrict__ boxes, int* __restrict__ order, int n_boxes)
{
    __shared__ int cursor[64];
    const int tid = threadIdx.x;
    if (tid < 64) cursor[tid] = 0;
    __syncthreads();

    // histogram over 8x8 spatial buckets of (x1,y1)
    for (int i = tid; i < n_boxes; i += 256) {
        const int x1 = boxes[i * 4 + 0];
        const int y1 = boxes[i * 4 + 1];
        const int key = ((y1 >> 4) << 3) | (x1 >> 4);
        atomicAdd(&cursor[key], 1);
    }
    __syncthreads();

    if (tid == 0) {
        int run = 0;
        for (int k = 0; k < 64; ++k) {
            int c = cursor[k];
            cursor[k] = run;
            run += c;
        }
    }
    __syncthreads();

    for (int i = tid; i < n_boxes; i += 256) {
        const int x1 = boxes[i * 4 + 0];
        const int y1 = boxes[i * 4 + 1];
        const int key = ((y1 >> 4) << 3) | (x1 >> 4);
        const int pos = atomicAdd(&cursor[key], 1);
        order[pos] = i;   // intra-bucket order nondeterministic; output invariant
    }
}

__global__ __launch_bounds__(256) void roi_pool_kernel(
    const float* __restrict__ fm,
    const int* __restrict__ boxes,
    const int* __restrict__ order,
    float* __restrict__ out,
    int n_samples)  // N * 49
{
    // chunked bijective XCD swizzle
    const int nb  = gridDim.x;
    const int b   = blockIdx.x;
    const int q   = nb >> 3;
    const int r   = nb & 7;
    const int xcd = b & 7;
    const int idx = b >> 3;
    const int sb  = (xcd < r ? xcd * (q + 1) : r * (q + 1) + (xcd - r) * q) + idx;

    const int lane = threadIdx.x & 63;
    // sample id in sorted order, wave-uniform on the scalar pipe
    const int wave = __builtin_amdgcn_readfirstlane((sb << 2) + (threadIdx.x >> 6));
    if (wave >= n_samples) return;

    const int sorted_box = wave / NSAMP;
    const int s   = wave - sorted_box * NSAMP;
    const int py  = s / ANCH;
    const int px  = s - py * ANCH;
    const int box = order[sorted_box];          // original box index

    const int x1 = boxes[box * 4 + 0];
    const int y1 = boxes[box * 4 + 1];
    const int x2 = boxes[box * 4 + 2];
    const int y2 = boxes[box * 4 + 3];

    // ---- axis_samples(y1, y2) at index py ----
    const float spany = (float)(y2 - y1);
    float sy = ((float)py + 0.5f) * (spany / (float)ANCH) - 0.5f;
    sy = fminf(fmaxf(sy, 0.0f), fmaxf(spany - 1.0f, 0.0f));
    const int iy0 = (int)floorf(sy);
    const int iy1 = min(iy0 + 1, y2 - y1 - 1);
    const float fy = sy - (float)iy0;
    const int ys0 = iy0 + y1;
    const int ys1 = iy1 + y1;

    // ---- axis_samples(x1, x2) at index px ----
    const float spanx = (float)(x2 - x1);
    float sx = ((float)px + 0.5f) * (spanx / (float)ANCH) - 0.5f;
    sx = fminf(fmaxf(sx, 0.0f), fmaxf(spanx - 1.0f, 0.0f));
    const int ix0 = (int)floorf(sx);
    const int ix1 = min(ix0 + 1, x2 - x1 - 1);
    const float fx = sx - (float)ix0;
    const int xs0 = ix0 + x1;
    const int xs1 = ix1 + x1;

    const f4* p00 = (const f4*)(fm + ((size_t)ys0 * FM_W + xs0) * FM_C);
    const f4* p01 = (const f4*)(fm + ((size_t)ys0 * FM_W + xs1) * FM_C);
    const f4* p10 = (const f4*)(fm + ((size_t)ys1 * FM_W + xs0) * FM_C);
    const f4* p11 = (const f4*)(fm + ((size_t)ys1 * FM_W + xs1) * FM_C);

    const f4 v00 = p00[lane];
    const f4 v01 = p01[lane];
    const f4 v10 = p10[lane];
    const f4 v11 = p11[lane];

    const float gx = 1.0f - fx;
    const float gy = 1.0f - fy;

    // Match reference order: x-lerp then y-lerp
    f4 res;
    #pragma unroll
    for (int c = 0; c < 4; ++c) {
        float top = v00[c] * gx + v01[c] * fx;
        float bot = v10[c] * gx + v11[c] * fx;
        res[c] = top * gy + bot * fy;
    }

    // write at ORIGINAL box position => output independent of sort order.
    // PLAIN cached store (the round-11 experiment): let L2/L3 absorb the
    // 100 MB output instead of forcing an HBM drain via nontemporal.
    f4* dst = (f4*)(out + ((size_t)box * NSAMP + s) * FM_C);
    dst[lane] = res;
}

extern "C" void kernel_launch(void* const* d_in, const int* in_sizes, int n_in,
                              void* d_out, int out_size, void* d_ws, size_t ws_size,
                              hipStream_t stream) {
    const float* fm    = (const float*)d_in[0];   // (1,128,128,256) fp32
    const int*   boxes = (const int*)d_in[1];     // (N,4) int32
    // d_in[2] = anchor_size scalar (7); layout constants hard-coded to setup.

    const int N = in_sizes[1] / 4;
    const int n_samples = N * NSAMP;

    float* out  = (float*)d_out;
    int* order  = (int*)d_ws;                      // N ints of scratch

    sort_boxes_kernel<<<1, 256, 0, stream>>>(boxes, order, N);

    const int threads = 256;                       // 4 waves/block, full occupancy
    const int waves_per_block = threads / 64;
    const int grid = (n_samples + waves_per_block - 1) / waves_per_block;

    roi_pool_kernel<<<grid, threads, 0, stream>>>(fm, boxes, order, out, n_samples);
}